// Round 9
// baseline (194.933 us; speedup 1.0000x reference)
//
#include <hip/hip_runtime.h>
#include <hip/hip_bf16.h>
#include <cstdint>
#include <cstddef>

typedef __bf16 bf16_t;
typedef __bf16 bf16x8 __attribute__((ext_vector_type(8)));
typedef __bf16 bf16x4 __attribute__((ext_vector_type(4)));
typedef float f32x4 __attribute__((ext_vector_type(4)));

#define DEVINL static __device__ __forceinline__

constexpr int B_ = 4, S_ = 2048, D_ = 512, H_ = 8, HD_ = 64;
constexpr int M_ = B_ * S_;   // 8192
constexpr int NIN = 14;

DEVINL bf16x8 load8g(const bf16_t* p) { return *reinterpret_cast<const bf16x8*>(p); }

// XOR-swizzle: permute 16B-chunk index by row&7 within each aligned 64-elem group.
DEVINL int swcol(int col, int row) {
  return (col & ~63) | ((((col >> 3) ^ row) & 7) << 3) | (col & 7);
}

// K-specific swizzle keyed on row bits {0,1,3} (attn kf reads permuted rows).
DEVINL int pK(int row) { return (row & 3) | (((row >> 3) & 1) << 2); }
DEVINL int swcolK(int col, int row) {
  return (col & ~63) | ((((col >> 3) ^ pK(row)) & 7) << 3) | (col & 7);
}

// async global->LDS, 16 B/lane. LDS dest is wave-uniform base + lane*16 (m104/m108).
DEVINL void gl2lds(const bf16_t* g, bf16_t* l) {
  __builtin_amdgcn_global_load_lds(
      (const __attribute__((address_space(1))) void*)g,
      (__attribute__((address_space(3))) void*)l, 16, 0, 0);
}

DEVINL void stage16(bf16_t* dst, const void* src, size_t off, bool f32) {
  if (f32) {
    const float* p = (const float*)src + off;
    bf16x8 v0, v1;
#pragma unroll
    for (int j = 0; j < 8; ++j) { v0[j] = (bf16_t)p[j]; v1[j] = (bf16_t)p[8 + j]; }
    *reinterpret_cast<bf16x8*>(dst)     = v0;
    *reinterpret_cast<bf16x8*>(dst + 8) = v1;
  } else {
    const bf16_t* p = (const bf16_t*)src + off;
    *reinterpret_cast<bf16x8*>(dst)     = load8g(p);
    *reinterpret_cast<bf16x8*>(dst + 8) = load8g(p + 8);
  }
}

DEVINL float readf(const void* p, size_t i, bool f32) {
  return f32 ? ((const float*)p)[i] : (float)((const bf16_t*)p)[i];
}

// ---------------- dtype detect: flags[i]=1 iff input i is float32 ----------------
struct DetectArgs { const uint16_t* p[NIN]; int n[NIN]; int* flags; };

__global__ __launch_bounds__(64) void detect_kernel(DetectArgs a) {
  const int z = blockIdx.x;
  const uint16_t* p = a.p[z];
  const int n = a.n[z];
  const int t = threadIdx.x;
  int cnt = 0;
  for (int i = t; i < n; i += 64) {
    const int e = (p[i] >> 7) & 0xFF;
    cnt += (e >= 200);
  }
#pragma unroll
  for (int off = 32; off > 0; off >>= 1) cnt += __shfl_down(cnt, off, 64);
  if (t == 0) a.flags[z] = (cnt > 16) ? 1 : 0;
}

// -------- prep: cvt (mod feats -> bf16 swizzled) + weight transpose, ONE dispatch --------
struct PrepArgs {
  const void* csrc[2]; bf16_t* cdst[2]; int cidx[2];
  const void* wsrc[6]; int wIdx[6]; bf16_t* wdst[6];
  const int* flags;
};

__global__ __launch_bounds__(256) void prep_kernel(PrepArgs a) {
  __shared__ bf16_t tile[64][80];
  const int bid = blockIdx.x;
  if (bid < 4096) {
    // ---- cvt part: 2 mats x 2048 blocks ----
    const int z = bid >> 11;
    const int bx = bid & 2047;
    const bool f32 = a.flags[a.cidx[z]] != 0;
    const size_t i = ((size_t)bx * 256 + threadIdx.x) * 8;
    const int row = (int)(i >> 9);
    const int col = (int)(i & 511);
    bf16_t* dst = a.cdst[z] + (size_t)row * 512 + swcol(col, row);
    if (f32) {
      const float* p = (const float*)a.csrc[z] + i;
      bf16x8 v;
#pragma unroll
      for (int j = 0; j < 8; ++j) v[j] = (bf16_t)p[j];
      *reinterpret_cast<bf16x8*>(dst) = v;
    } else {
      *reinterpret_cast<bf16x8*>(dst) = load8g((const bf16_t*)a.csrc[z] + i);
    }
  } else {
    // ---- transpose part: 6 weights x 64 tiles ----
    const int rem = bid - 4096;
    const int w = rem >> 6;
    const int r6 = rem & 63;
    const int k0 = (r6 & 7) * 64, n0 = (r6 >> 3) * 64;
    const void* src = a.wsrc[w];
    const bool f32 = a.flags[a.wIdx[w]] != 0;
    bf16_t* dst = a.wdst[w];
    const int t = threadIdx.x;
    const int r = t >> 2, c0 = (t & 3) * 16;
    stage16(&tile[r][c0], src, (size_t)(k0 + r) * 512 + n0 + c0, f32);
    __syncthreads();
    const int orow = n0 + r;
    bf16_t* o = dst + (size_t)orow * 512;
#pragma unroll
    for (int half = 0; half < 2; ++half) {
      bf16x8 ov;
#pragma unroll
      for (int j = 0; j < 8; ++j) ov[j] = tile[c0 + half * 8 + j][r];
      *reinterpret_cast<bf16x8*>(o + swcol(k0 + c0 + half * 8, orow)) = ov;
    }
  }
}

// ---- GEMM + bias, 128x64 tile, BK=64, 512 thr / 8 waves (16-row strip per wave).
// 3-slot LDS ring, fused {s_waitcnt vmcnt(3); s_barrier}, prefetch distance 2. ----
struct GemmBatch {
  const bf16_t* A[3];
  const bf16_t* Bt[3];
  const void* bias[3]; int bIdx[3];
  void* C[3];          int cIdx[3];
  const int* flags;
};

__global__ __launch_bounds__(512) void gemm_bt_kernel(GemmBatch args) {
  constexpr int K = 512, N = 512;
  __shared__ bf16_t As[3][128][64];   // 48 KB
  __shared__ bf16_t Bs[3][64][64];    // 24 KB
  const int z = blockIdx.z;
  const bf16_t* Ag  = args.A[z];
  const bf16_t* Btg = args.Bt[z];
  const int m0 = blockIdx.x * 128, n0 = blockIdx.y * 64;
  const int t = threadIdx.x, lane = t & 63, wave = t >> 6;   // wave 0..7
  const int l16 = lane & 15, quad = lane >> 4;
  const int wm = wave * 16;
  const int lr = lane >> 3, lc = (lane & 7) * 8;   // 8 rows x 128 B per gl2lds

  auto stage = [&](int slot, int k0) {
#pragma unroll
    for (int s = 0; s < 2; ++s) {
      const int r = wm + s * 8;
      gl2lds(Ag + (size_t)(m0 + r + lr) * K + k0 + lc, &As[slot][r][0]);
    }
    gl2lds(Btg + (size_t)(n0 + wave * 8 + lr) * K + k0 + lc, &Bs[slot][wave * 8][0]);
  };

  f32x4 acc[4] = {};

  stage(0, 0);
  stage(1, 64);

  constexpr int NT = K / 64;   // 8
  int cur = 0;
  for (int kt = 0; kt < NT - 1; ++kt) {
    asm volatile("s_waitcnt vmcnt(3)\n\ts_barrier" ::: "memory");
    __builtin_amdgcn_sched_barrier(0);
    if (kt + 2 < NT) {
      const int slot2 = cur == 0 ? 2 : cur - 1;
      stage(slot2, (kt + 2) * 64);
    }
#pragma unroll
    for (int ks = 0; ks < 2; ++ks) {
      const int sw = swcol(ks * 32 + quad * 8, l16);
      bf16x8 af = *reinterpret_cast<const bf16x8*>(&As[cur][wm + l16][sw]);
      bf16x8 bfr[4];
#pragma unroll
      for (int j = 0; j < 4; ++j)
        bfr[j] = *reinterpret_cast<const bf16x8*>(&Bs[cur][j * 16 + l16][sw]);
#pragma unroll
      for (int j = 0; j < 4; ++j)
        acc[j] = __builtin_amdgcn_mfma_f32_16x16x32_bf16(af, bfr[j], acc[j], 0, 0, 0);
    }
    cur = (cur == 2) ? 0 : cur + 1;
  }
  asm volatile("s_waitcnt vmcnt(0)\n\ts_barrier" ::: "memory");
  __builtin_amdgcn_sched_barrier(0);
#pragma unroll
  for (int ks = 0; ks < 2; ++ks) {
    const int sw = swcol(ks * 32 + quad * 8, l16);
    bf16x8 af = *reinterpret_cast<const bf16x8*>(&As[cur][wm + l16][sw]);
    bf16x8 bfr[4];
#pragma unroll
    for (int j = 0; j < 4; ++j)
      bfr[j] = *reinterpret_cast<const bf16x8*>(&Bs[cur][j * 16 + l16][sw]);
#pragma unroll
    for (int j = 0; j < 4; ++j)
      acc[j] = __builtin_amdgcn_mfma_f32_16x16x32_bf16(af, bfr[j], acc[j], 0, 0, 0);
  }

  // epilogue (flags read only now -> no VMEM during loop besides gl2lds)
  const void* biag = args.bias[z];
  void* Cg         = args.C[z];
  const bool bf32 = args.bIdx[z] >= 0 && args.flags[args.bIdx[z]];
  const bool cf32 = args.cIdx[z] >= 0 && args.flags[args.cIdx[z]];
#pragma unroll
  for (int j = 0; j < 4; ++j) {
    const int col = n0 + j * 16 + l16;
    const float bv = readf(biag, col, bf32);
    const int rowb = m0 + wm + quad * 4;
#pragma unroll
    for (int r = 0; r < 4; ++r) {
      const size_t idx = (size_t)(rowb + r) * N + col;
      const float v = acc[j][r] + bv;
      if (cf32) ((float*)Cg)[idx] = v;
      else      ((bf16_t*)Cg)[idx] = (bf16_t)v;
    }
  }
}

// ---- FUSED K/V/scale/shift projection + modulation: 1024 thr / 16 waves,
// 144 KB 3-slot ring, 4 waves/SIMD, vmcnt(3). Modulation in-register, f32 scale/shift.
struct KsvArgs {
  const bf16_t* A;          // m2b (swizzled)
  const bf16_t* Bt[4];      // wtk, wtv, wts, wtsh (swizzled)
  const void* bias[4]; int bIdx[4];   // bk, bv, bs, bsh
  bf16_t* Kmod;             // [M,512] swcolK (attn kf consumer)
  bf16_t* VtT;              // [B][H][HD][S] swcol
  const int* flags;
};

__global__ __launch_bounds__(1024) void ksv_kernel(KsvArgs args) {
  constexpr int K = 512;
  __shared__ bf16_t As[3][128][64];       // 48 KB
  __shared__ bf16_t Bs[3][4][64][64];     // 96 KB
  const int m0 = blockIdx.x * 128, n0 = blockIdx.y * 64;
  const int t = threadIdx.x, lane = t & 63, wave = t >> 6;   // 0..15
  const int l16 = lane & 15, quad = lane >> 4;
  const int wm = (wave >> 2) * 32;        // 0,32,64,96
  const int wn = (wave & 3) * 16;         // 0,16,32,48
  const int lr = lane >> 3, lc = (lane & 7) * 8;

  auto stage = [&](int slot, int k0) {
    // A: 16 loads, one per wave
    gl2lds(args.A + (size_t)(m0 + wave * 8 + lr) * K + k0 + lc, &As[slot][wave * 8][0]);
    // B: 32 loads, two per wave: mat = wave>>2, rows (wave&3)*16 + {0,8}
    const int mat = wave >> 2;
    const int rb = (wave & 3) * 16;
#pragma unroll
    for (int s = 0; s < 2; ++s) {
      const int r = rb + s * 8;
      gl2lds(args.Bt[mat] + (size_t)(n0 + r + lr) * K + k0 + lc, &Bs[slot][mat][r][0]);
    }
  };

  f32x4 acc[4][2] = {};   // [mat: K,V,S,Sh][mi]

  stage(0, 0);
  stage(1, 64);

  constexpr int NT = K / 64;   // 8
  int cur = 0;
  for (int kt = 0; kt < NT - 1; ++kt) {
    asm volatile("s_waitcnt vmcnt(3)\n\ts_barrier" ::: "memory");
    __builtin_amdgcn_sched_barrier(0);
    if (kt + 2 < NT) {
      const int slot2 = cur == 0 ? 2 : cur - 1;
      stage(slot2, (kt + 2) * 64);
    }
#pragma unroll
    for (int ks = 0; ks < 2; ++ks) {
      const int sw = swcol(ks * 32 + quad * 8, l16);
      bf16x8 af[2], bfr[4];
#pragma unroll
      for (int mi = 0; mi < 2; ++mi)
        af[mi] = *reinterpret_cast<const bf16x8*>(&As[cur][wm + mi * 16 + l16][sw]);
#pragma unroll
      for (int mat = 0; mat < 4; ++mat)
        bfr[mat] = *reinterpret_cast<const bf16x8*>(&Bs[cur][mat][wn + l16][sw]);
#pragma unroll
      for (int mat = 0; mat < 4; ++mat)
#pragma unroll
        for (int mi = 0; mi < 2; ++mi)
          acc[mat][mi] = __builtin_amdgcn_mfma_f32_16x16x32_bf16(af[mi], bfr[mat], acc[mat][mi], 0, 0, 0);
    }
    cur = (cur == 2) ? 0 : cur + 1;
  }
  asm volatile("s_waitcnt vmcnt(0)\n\ts_barrier" ::: "memory");
  __builtin_amdgcn_sched_barrier(0);
#pragma unroll
  for (int ks = 0; ks < 2; ++ks) {
    const int sw = swcol(ks * 32 + quad * 8, l16);
    bf16x8 af[2], bfr[4];
#pragma unroll
    for (int mi = 0; mi < 2; ++mi)
      af[mi] = *reinterpret_cast<const bf16x8*>(&As[cur][wm + mi * 16 + l16][sw]);
#pragma unroll
    for (int mat = 0; mat < 4; ++mat)
      bfr[mat] = *reinterpret_cast<const bf16x8*>(&Bs[cur][mat][wn + l16][sw]);
#pragma unroll
    for (int mat = 0; mat < 4; ++mat)
#pragma unroll
      for (int mi = 0; mi < 2; ++mi)
        acc[mat][mi] = __builtin_amdgcn_mfma_f32_16x16x32_bf16(af[mi], bfr[mat], acc[mat][mi], 0, 0, 0);
  }

  // fused epilogue: s = S+bs, sh = Sh+bsh (f32, unrounded); K' = (K+bk)*s+sh; V' likewise.
  const int col = n0 + wn + l16;
  const float bk  = readf(args.bias[0], col, args.bIdx[0] >= 0 && args.flags[args.bIdx[0]]);
  const float bv  = readf(args.bias[1], col, args.bIdx[1] >= 0 && args.flags[args.bIdx[1]]);
  const float bs  = readf(args.bias[2], col, args.bIdx[2] >= 0 && args.flags[args.bIdx[2]]);
  const float bsh = readf(args.bias[3], col, args.bIdx[3] >= 0 && args.flags[args.bIdx[3]]);
  const int hh = col >> 6, dd = col & 63;
#pragma unroll
  for (int mi = 0; mi < 2; ++mi) {
    const int rowb = m0 + wm + mi * 16 + quad * 4;
    bf16x4 vpack;
#pragma unroll
    for (int r = 0; r < 4; ++r) {
      const int row = rowb + r;
      const float s  = acc[2][mi][r] + bs;
      const float sh = acc[3][mi][r] + bsh;
      const float kk = fmaf(acc[0][mi][r] + bk, s, sh);
      const float vv = fmaf(acc[1][mi][r] + bv, s, sh);
      args.Kmod[(size_t)row * 512 + swcolK(col, row)] = (bf16_t)kk;
      vpack[r] = (bf16_t)vv;
    }
    const int bb = rowb >> 11;      // batch (tile never crosses batch)
    const int ss = rowb & 2047;     // seq (multiple of 4)
    *reinterpret_cast<bf16x4*>(
        args.VtT + (((size_t)(bb * H_ + hh)) * HD_ + dd) * S_ + swcol(ss, dd)) = vpack;
  }
}

// ---- flash attention v14: v12 main loop + FUSED Q-projection prologue.
// Block (b,h,qt) computes its own 128x64 Q tile = m1b[rows] @ Wq[:, h*64..+64] + bq
// (each Q tile is consumed by exactly ONE attn block -> fusion is traffic-neutral,
// deletes the qproj dispatch and the 16 MB q_buf round-trip). Prologue: 8 k-tiles,
// dist-2 counted-vmcnt ring reusing Ks/Vs as the 128-row A slots + Xs for Wq.
// Q^T computed via mfma(wtq, m1b) so lane's C-col = its own q-row; bias f32, one
// bf16 rounding (same arithmetic as old qproj). LDS 72 KB -> 2 blocks/CU.
__global__ __launch_bounds__(512) void attn_kernel(const bf16_t* M1, const bf16_t* Wq,
                                                   const void* bq, const int* flags,
                                                   const bf16_t* Kb, const bf16_t* Vt,
                                                   bf16_t* O) {
  __shared__ bf16_t Ks[3][64][64];    // 24 KB (Q-A rows 0-63 in prologue; K ring in loop)
  __shared__ bf16_t Vs[3][64][64];    // 24 KB (Q-A rows 64-127; V ring)
  __shared__ bf16_t Xs[3][64][64];    // 24 KB (Wq tile in prologue; Qls after)
  const int i = blockIdx.x;
  const int xcd = i & 7, g = i >> 3;     // g in 0..63
  const int slice = xcd * 4 + (g & 3);   // (b,h): 4 slices per XCD
  const int qt = g >> 2;                 // 0..15
  const int b = slice >> 3, h = slice & 7;
  const int t = threadIdx.x, wave = t >> 6, lane = t & 63;   // wave 0..7
  const int l16 = lane & 15, quad = lane >> 4;
  const int q0 = qt * 128 + wave * 16;   // 16 q-rows per wave
  const int lr = lane >> 3, lc = (lane & 7) * 8;

  const size_t q0g = (size_t)b * S_ + qt * 128;   // global base row of this block's Q tile

  // ================= Q-GEMM prologue =================
  // A = m1b rows q0g..+128 (swizzled), B = wtq rows h*64..+64 (swizzled).
  auto qstage = [&](int set, int k0) {
#pragma unroll
    for (int s = 0; s < 2; ++s) {
      const int r = wave * 16 + s * 8;   // 0..120
      bf16_t* dst = (wave < 4) ? &Ks[set][r][0] : &Vs[set][r - 64][0];
      gl2lds(M1 + (q0g + r + lr) * D_ + k0 + lc, dst);
    }
    gl2lds(Wq + (size_t)(h * HD_ + wave * 8 + lr) * D_ + k0 + lc, &Xs[set][wave * 8][0]);
  };

  f32x4 qacc[4] = {};
  const bf16_t* brow = (wave < 4) ? &Ks[0][wave * 16][0] : &Vs[0][wave * 16 - 64][0];
  const int setstride = 64 * 64;   // elements between consecutive sets in Ks/Vs/Xs

  auto qcompute = [&](int set) {
    const bf16_t* bbase = brow + set * setstride;
#pragma unroll
    for (int ks = 0; ks < 2; ++ks) {
      const int sw = swcol(ks * 32 + quad * 8, l16);
      // B-operand: this wave's own 16 q-rows of m1b
      bf16x8 bf = *reinterpret_cast<const bf16x8*>(bbase + l16 * 64 + sw);
      bf16x8 af[4];
#pragma unroll
      for (int j = 0; j < 4; ++j)
        af[j] = *reinterpret_cast<const bf16x8*>(&Xs[set][j * 16 + l16][sw]);
#pragma unroll
      for (int j = 0; j < 4; ++j)
        qacc[j] = __builtin_amdgcn_mfma_f32_16x16x32_bf16(af[j], bf, qacc[j], 0, 0, 0);
    }
  };

  qstage(0, 0);
  qstage(1, 64);
  {
    constexpr int QNT = D_ / 64;   // 8
    int cur = 0;
    for (int kt = 0; kt < QNT - 1; ++kt) {
      asm volatile("s_waitcnt vmcnt(3)\n\ts_barrier" ::: "memory");
      __builtin_amdgcn_sched_barrier(0);
      if (kt + 2 < QNT) {
        const int slot2 = cur == 0 ? 2 : cur - 1;
        qstage(slot2, (kt + 2) * 64);
      }
      qcompute(cur);
      cur = (cur == 2) ? 0 : cur + 1;
    }
    asm volatile("s_waitcnt vmcnt(0)\n\ts_barrier" ::: "memory");
    __builtin_amdgcn_sched_barrier(0);
    qcompute(cur);
  }
  // bias (+bq) in f32, one rounding to bf16 — identical to old qproj->q_buf path
  const bool qbf32 = flags[3] != 0;
  __syncthreads();   // all waves done reading Xs B-frags before Qls overwrite
  bf16_t* qls = &Xs[0][0][0];   // [8 waves][16 q][64 d], spans Xs[0..1]
#pragma unroll
  for (int j = 0; j < 4; ++j) {
    bf16x4 pk;
#pragma unroll
    for (int r = 0; r < 4; ++r) {
      const int d = j * 16 + quad * 4 + r;
      pk[r] = (bf16_t)(qacc[j][r] + readf(bq, h * HD_ + d, qbf32));
    }
    *reinterpret_cast<bf16x4*>(&qls[wave * 1024 + l16 * 64 + swcol(j * 16 + quad * 4, l16)]) = pk;
  }
  __syncthreads();
  bf16x8 qf[2];
#pragma unroll
  for (int dc = 0; dc < 2; ++dc)
    qf[dc] = *reinterpret_cast<const bf16x8*>(&qls[wave * 1024 + l16 * 64 + swcol(dc * 32 + quad * 8, l16)]);
  // ================= end prologue =================

  bf16x8 ones;
#pragma unroll
  for (int j = 0; j < 8; ++j) ones[j] = (bf16_t)1.0f;

  f32x4 oacc[4] = {};
  f32x4 lacc = {};

  const size_t kbase = (size_t)b * S_ * D_ + h * HD_;
  const size_t vbase = ((size_t)(b * H_ + h)) * HD_ * S_;

  const int rbase = ((l16 >> 2) << 3) | (l16 & 3);
  int koff[2][4];   // [dc][j]
#pragma unroll
  for (int j = 0; j < 4; ++j) {
    const int rho = rbase + (j >> 1) * 32 + (j & 1) * 4;
#pragma unroll
    for (int dc = 0; dc < 2; ++dc)
      koff[dc][j] = rho * 64 + swcolK(dc * 32 + quad * 8, rho);
  }
  const int voff[2] = { swcol(quad * 8, l16), swcol(32 + quad * 8, l16) };

  auto stage = [&](int slot, int k0) {
    const int r = wave * 8;
    gl2lds(Kb + kbase + (size_t)(k0 + r + lr) * D_ + lc, &Ks[slot][r][0]);
    gl2lds(Vt + vbase + (size_t)(r + lr) * S_ + k0 + lc, &Vs[slot][r][0]);
  };

  constexpr float CE = 0.18033688011112042f;  // 0.125 * log2(e)

  auto compute = [&](int cur) {
    f32x4 sacc[4] = {};
    const bf16_t* ksbase = &Ks[cur][0][0];
#pragma unroll
    for (int dc = 0; dc < 2; ++dc) {
      bf16x8 kf[4];
#pragma unroll
      for (int j = 0; j < 4; ++j)
        kf[j] = *reinterpret_cast<const bf16x8*>(ksbase + koff[dc][j]);
#pragma unroll
      for (int j = 0; j < 4; ++j)
        sacc[j] = __builtin_amdgcn_mfma_f32_16x16x32_bf16(kf[j], qf[dc], sacc[j], 0, 0, 0);
    }
#pragma unroll
    for (int kc = 0; kc < 2; ++kc) {
      bf16x8 vf[4];
#pragma unroll
      for (int dj = 0; dj < 4; ++dj)
        vf[dj] = *reinterpret_cast<const bf16x8*>(&Vs[cur][dj * 16 + l16][voff[kc]]);
      bf16x8 bp;
#pragma unroll
      for (int r = 0; r < 4; ++r) {
        bp[r]     = (bf16_t)__builtin_amdgcn_exp2f(fminf(sacc[kc * 2][r]     * CE, 57.5f));
        bp[4 + r] = (bf16_t)__builtin_amdgcn_exp2f(fminf(sacc[kc * 2 + 1][r] * CE, 57.5f));
      }
#pragma unroll
      for (int dj = 0; dj < 4; ++dj)
        oacc[dj] = __builtin_amdgcn_mfma_f32_16x16x32_bf16(vf[dj], bp, oacc[dj], 0, 0, 0);
      lacc = __builtin_amdgcn_mfma_f32_16x16x32_bf16(ones, bp, lacc, 0, 0, 0);
    }
  };

  // drain bias/flag loads so the loop's vmcnt ledger counts only gl2lds ops
  asm volatile("s_waitcnt vmcnt(0)" ::: "memory");
  stage(0, 0);
  stage(1, 64);

  constexpr int NT = S_ / 64;   // 32
  int cur = 0;
  for (int kt = 0; kt < NT - 1; ++kt) {
    asm volatile("s_waitcnt vmcnt(2)\n\ts_barrier" ::: "memory");
    __builtin_amdgcn_sched_barrier(0);
    if (kt + 2 < NT) {
      const int slot2 = cur == 0 ? 2 : cur - 1;   // (kt+2)%3, freed at barrier above
      stage(slot2, (kt + 2) * 64);
    }
    compute(cur);
    cur = (cur == 2) ? 0 : cur + 1;
  }
  asm volatile("s_waitcnt vmcnt(0)\n\ts_barrier" ::: "memory");
  __builtin_amdgcn_sched_barrier(0);
  compute(cur);

  // ---- epilogue: O[q][d] = O^T[d][q] / l[q]; packed 8B stores, SWIZZLED (feeds g2) ----
  {
    const float linv = 1.0f / fmaxf(lacc[0], 1e-30f);
    const int q = q0 + l16;
    const size_t orow = ((size_t)b * S_ + q) * D_ + h * HD_;
#pragma unroll
    for (int dj = 0; dj < 4; ++dj) {
      bf16x4 pack;
#pragma unroll
      for (int r = 0; r < 4; ++r) pack[r] = (bf16_t)(oacc[dj][r] * linv);
      *reinterpret_cast<bf16x4*>(&O[orow + swcol(dj * 16 + quad * 4, q)]) = pack;
    }
  }
}

// ---------------- host launcher ----------------
extern "C" void kernel_launch(void* const* d_in, const int* in_sizes, int n_in,
                              void* d_out, int out_size, void* d_ws, size_t ws_size,
                              hipStream_t stream) {
  (void)n_in; (void)out_size; (void)ws_size;

  char* ws = (char*)d_ws;
  auto alloc = [&](size_t bytes) -> char* {
    char* p = ws; ws += (bytes + 255) & ~(size_t)255; return p;
  };
  int* flags = (int*)alloc(64 * sizeof(int));
  const size_t wbytes = (size_t)512 * 512 * sizeof(bf16_t);
  const size_t fbytes = (size_t)M_ * D_ * sizeof(bf16_t);
  bf16_t* wt    = (bf16_t*)alloc(6 * wbytes);  // 3 MB (swizzled)
  bf16_t* m1b   = (bf16_t*)alloc(fbytes);      // 8 MB mod1 bf16 swizzled (live into attn)
  bf16_t* m2b   = (bf16_t*)alloc(fbytes);      // 8 MB mod2 bf16 swizzled
  bf16_t* vtb   = (bf16_t*)alloc(fbytes);      // 8 MB V^T (swizzled)
  bf16_t* atmp  = (bf16_t*)alloc(fbytes);      // 8 MB attn output (swizzled)
  bf16_t* kmod  = (bf16_t*)alloc(fbytes);      // 8 MB swizzled (swcolK)
  bf16_t* attn_b = atmp;

  bf16_t* wtq  = wt + 0 * 512 * 512;
  bf16_t* wtk  = wt + 1 * 512 * 512;
  bf16_t* wtv  = wt + 2 * 512 * 512;
  bf16_t* wts  = wt + 3 * 512 * 512;
  bf16_t* wtsh = wt + 4 * 512 * 512;
  bf16_t* wto  = wt + 5 * 512 * 512;

  DetectArgs da;
  for (int i = 0; i < NIN; ++i) {
    da.p[i] = (const uint16_t*)d_in[i];
    da.n[i] = in_sizes[i] < 2048 ? in_sizes[i] : 2048;
  }
  da.flags = flags;
  hipLaunchKernelGGL(detect_kernel, dim3(NIN), dim3(64), 0, stream, da);

  // prep: cvt (4096 blocks) + weight transpose (384 blocks), one dispatch
  PrepArgs pa;
  pa.csrc[0] = d_in[0]; pa.cdst[0] = m1b; pa.cidx[0] = 0;
  pa.csrc[1] = d_in[1]; pa.cdst[1] = m2b; pa.cidx[1] = 1;
  const int widx[6] = {2, 4, 6, 10, 12, 8};
  bf16_t* wdst[6] = {wtq, wtk, wtv, wts, wtsh, wto};
  for (int i = 0; i < 6; ++i) { pa.wsrc[i] = d_in[widx[i]]; pa.wIdx[i] = widx[i]; pa.wdst[i] = wdst[i]; }
  pa.flags = flags;
  hipLaunchKernelGGL(prep_kernel, dim3(4096 + 384), dim3(256), 0, stream, pa);

  // ksv: fused K/V/scale/shift + modulation — 512 blocks x 1024 thr (4 waves/SIMD)
  KsvArgs kv;
  kv.A = m2b;
  kv.Bt[0] = wtk; kv.Bt[1] = wtv; kv.Bt[2] = wts; kv.Bt[3] = wtsh;
  kv.bias[0] = d_in[5];  kv.bIdx[0] = 5;
  kv.bias[1] = d_in[7];  kv.bIdx[1] = 7;
  kv.bias[2] = d_in[11]; kv.bIdx[2] = 11;
  kv.bias[3] = d_in[13]; kv.bIdx[3] = 13;
  kv.Kmod = kmod; kv.VtT = vtb;
  kv.flags = flags;
  hipLaunchKernelGGL(ksv_kernel, dim3(M_ / 128, 8), dim3(1024), 0, stream, kv);

  // attn (+ fused Q projection): 512 blocks x 512 threads, 3-slot pipeline
  hipLaunchKernelGGL(attn_kernel, dim3(512), dim3(512), 0, stream,
                     m1b, wtq, d_in[3], flags, kmod, vtb, attn_b);

  // g2: out = attn @ Wo^T + bo — 512 blocks x 512 thr
  GemmBatch g2;
  for (int i = 0; i < 3; ++i) {
    g2.A[i] = attn_b;
    g2.Bt[i] = wto;
    g2.bias[i] = d_in[9]; g2.bIdx[i] = 9;
    g2.C[i] = d_out; g2.cIdx[i] = 0;
  }
  g2.flags = flags;
  hipLaunchKernelGGL(gemm_bt_kernel, dim3(M_ / 128, 8, 1), dim3(512), 0, stream, g2);
}

// Round 10
// 187.166 us; speedup vs baseline: 1.0415x; 1.0415x over previous
//
#include <hip/hip_runtime.h>
#include <hip/hip_bf16.h>
#include <cstdint>
#include <cstddef>

typedef __bf16 bf16_t;
typedef __bf16 bf16x8 __attribute__((ext_vector_type(8)));
typedef __bf16 bf16x4 __attribute__((ext_vector_type(4)));
typedef float f32x4 __attribute__((ext_vector_type(4)));

#define DEVINL static __device__ __forceinline__

constexpr int B_ = 4, S_ = 2048, D_ = 512, H_ = 8, HD_ = 64;
constexpr int M_ = B_ * S_;   // 8192
constexpr int NIN = 14;

DEVINL bf16x8 load8g(const bf16_t* p) { return *reinterpret_cast<const bf16x8*>(p); }

// XOR-swizzle: permute 16B-chunk index by row&7 within each aligned 64-elem group.
DEVINL int swcol(int col, int row) {
  return (col & ~63) | ((((col >> 3) ^ row) & 7) << 3) | (col & 7);
}

// K-specific swizzle keyed on row bits {0,1,3} (attn kf reads permuted rows).
DEVINL int pK(int row) { return (row & 3) | (((row >> 3) & 1) << 2); }
DEVINL int swcolK(int col, int row) {
  return (col & ~63) | ((((col >> 3) ^ pK(row)) & 7) << 3) | (col & 7);
}

// async global->LDS, 16 B/lane. LDS dest is wave-uniform base + lane*16 (m104/m108).
DEVINL void gl2lds(const bf16_t* g, bf16_t* l) {
  __builtin_amdgcn_global_load_lds(
      (const __attribute__((address_space(1))) void*)g,
      (__attribute__((address_space(3))) void*)l, 16, 0, 0);
}

DEVINL void stage16(bf16_t* dst, const void* src, size_t off, bool f32) {
  if (f32) {
    const float* p = (const float*)src + off;
    bf16x8 v0, v1;
#pragma unroll
    for (int j = 0; j < 8; ++j) { v0[j] = (bf16_t)p[j]; v1[j] = (bf16_t)p[8 + j]; }
    *reinterpret_cast<bf16x8*>(dst)     = v0;
    *reinterpret_cast<bf16x8*>(dst + 8) = v1;
  } else {
    const bf16_t* p = (const bf16_t*)src + off;
    *reinterpret_cast<bf16x8*>(dst)     = load8g(p);
    *reinterpret_cast<bf16x8*>(dst + 8) = load8g(p + 8);
  }
}

DEVINL float readf(const void* p, size_t i, bool f32) {
  return f32 ? ((const float*)p)[i] : (float)((const bf16_t*)p)[i];
}

// block-wide dtype sniff: true iff data looks like f32 (exponent-bit heuristic,
// same as the old detect_kernel). 256 threads; uses dsum[4] + 2 barriers.
DEVINL bool block_detect(const uint16_t* p, int n, int* dsum) {
  const int t = threadIdx.x;
  int cnt = 0;
  for (int i = t; i < n; i += 256) cnt += (((p[i] >> 7) & 0xFF) >= 200);
#pragma unroll
  for (int off = 32; off > 0; off >>= 1) cnt += __shfl_down(cnt, off, 64);
  if ((t & 63) == 0) dsum[t >> 6] = cnt;
  __syncthreads();
  const int tot = dsum[0] + dsum[1] + dsum[2] + dsum[3];
  __syncthreads();
  return tot > 16;
}

// -------- prep: cvt (16 elem/thr) + weight transpose + flag detect, ONE dispatch --------
// Blocks [0,2048): cvt (2 mats x 1024); [2048,2432): transpose (6 w x 64 tiles);
// [2432,2446): flags[z] for downstream bias/output dtype. cvt/transpose self-detect
// their source dtype (2048-elem scan, L2-hot) -> no cross-block flag dependency.
struct PrepArgs {
  const void* csrc[2]; bf16_t* cdst[2];
  const void* wsrc[6]; bf16_t* wdst[6];
  const uint16_t* dp[NIN]; int dn[NIN];
  int* flags;
};

__global__ __launch_bounds__(256) void prep_kernel(PrepArgs a) {
  __shared__ bf16_t tile[64][80];
  __shared__ int dsum[4];
  const int bid = blockIdx.x;
  const int t = threadIdx.x;
  if (bid < 2048) {
    // ---- cvt: 16 elems/thread, swizzled bf16 output ----
    const int z = bid >> 10;
    const bool f32 = block_detect((const uint16_t*)a.csrc[z], 2048, dsum);
    const size_t i = ((size_t)(bid & 1023) * 256 + t) * 16;
    const int row = (int)(i >> 9);
    const int col = (int)(i & 511);
    bf16_t* dst = a.cdst[z] + (size_t)row * 512;
    bf16x8 v0, v1;
    if (f32) {
      const float* p = (const float*)a.csrc[z] + i;
      const f32x4 f0 = *reinterpret_cast<const f32x4*>(p);
      const f32x4 f1 = *reinterpret_cast<const f32x4*>(p + 4);
      const f32x4 f2 = *reinterpret_cast<const f32x4*>(p + 8);
      const f32x4 f3 = *reinterpret_cast<const f32x4*>(p + 12);
#pragma unroll
      for (int j = 0; j < 4; ++j) {
        v0[j] = (bf16_t)f0[j]; v0[4 + j] = (bf16_t)f1[j];
        v1[j] = (bf16_t)f2[j]; v1[4 + j] = (bf16_t)f3[j];
      }
    } else {
      const bf16_t* p = (const bf16_t*)a.csrc[z] + i;
      v0 = load8g(p); v1 = load8g(p + 8);
    }
    *reinterpret_cast<bf16x8*>(dst + swcol(col, row))     = v0;
    *reinterpret_cast<bf16x8*>(dst + swcol(col + 8, row)) = v1;
  } else if (bid < 2432) {
    // ---- transpose: WT[n][k] = W[k][n], swizzled output ----
    const int rem = bid - 2048;
    const int w = rem >> 6;
    const int r6 = rem & 63;
    const int k0 = (r6 & 7) * 64, n0 = (r6 >> 3) * 64;
    const void* src = a.wsrc[w];
    const bool f32 = block_detect((const uint16_t*)src, 2048, dsum);
    bf16_t* dst = a.wdst[w];
    const int r = t >> 2, c0 = (t & 3) * 16;
    stage16(&tile[r][c0], src, (size_t)(k0 + r) * 512 + n0 + c0, f32);
    __syncthreads();
    const int orow = n0 + r;
    bf16_t* o = dst + (size_t)orow * 512;
#pragma unroll
    for (int half = 0; half < 2; ++half) {
      bf16x8 ov;
#pragma unroll
      for (int j = 0; j < 8; ++j) ov[j] = tile[c0 + half * 8 + j][r];
      *reinterpret_cast<bf16x8*>(o + swcol(k0 + c0 + half * 8, orow)) = ov;
    }
  } else {
    // ---- flag detect for downstream consumers (biases, output dtype) ----
    const int z = bid - 2432;
    const bool f32 = block_detect(a.dp[z], a.dn[z], dsum);
    if (t == 0) a.flags[z] = f32 ? 1 : 0;
  }
}

// ---- GEMM + bias, 128x64 tile, BK=64, 512 thr / 8 waves (16-row strip per wave).
// 3-slot LDS ring, fused {s_waitcnt vmcnt(3); s_barrier}, prefetch distance 2. ----
struct GemmBatch {
  const bf16_t* A[3];
  const bf16_t* Bt[3];
  const void* bias[3]; int bIdx[3];
  void* C[3];          int cIdx[3];
  const int* flags;
};

__global__ __launch_bounds__(512) void gemm_bt_kernel(GemmBatch args) {
  constexpr int K = 512, N = 512;
  __shared__ bf16_t As[3][128][64];   // 48 KB
  __shared__ bf16_t Bs[3][64][64];    // 24 KB
  const int z = blockIdx.z;
  const bf16_t* Ag  = args.A[z];
  const bf16_t* Btg = args.Bt[z];
  const int m0 = blockIdx.x * 128, n0 = blockIdx.y * 64;
  const int t = threadIdx.x, lane = t & 63, wave = t >> 6;   // wave 0..7
  const int l16 = lane & 15, quad = lane >> 4;
  const int wm = wave * 16;
  const int lr = lane >> 3, lc = (lane & 7) * 8;   // 8 rows x 128 B per gl2lds

  auto stage = [&](int slot, int k0) {
#pragma unroll
    for (int s = 0; s < 2; ++s) {
      const int r = wm + s * 8;
      gl2lds(Ag + (size_t)(m0 + r + lr) * K + k0 + lc, &As[slot][r][0]);
    }
    gl2lds(Btg + (size_t)(n0 + wave * 8 + lr) * K + k0 + lc, &Bs[slot][wave * 8][0]);
  };

  f32x4 acc[4] = {};

  stage(0, 0);
  stage(1, 64);

  constexpr int NT = K / 64;   // 8
  int cur = 0;
  for (int kt = 0; kt < NT - 1; ++kt) {
    asm volatile("s_waitcnt vmcnt(3)\n\ts_barrier" ::: "memory");
    __builtin_amdgcn_sched_barrier(0);
    if (kt + 2 < NT) {
      const int slot2 = cur == 0 ? 2 : cur - 1;
      stage(slot2, (kt + 2) * 64);
    }
#pragma unroll
    for (int ks = 0; ks < 2; ++ks) {
      const int sw = swcol(ks * 32 + quad * 8, l16);
      bf16x8 af = *reinterpret_cast<const bf16x8*>(&As[cur][wm + l16][sw]);
      bf16x8 bfr[4];
#pragma unroll
      for (int j = 0; j < 4; ++j)
        bfr[j] = *reinterpret_cast<const bf16x8*>(&Bs[cur][j * 16 + l16][sw]);
#pragma unroll
      for (int j = 0; j < 4; ++j)
        acc[j] = __builtin_amdgcn_mfma_f32_16x16x32_bf16(af, bfr[j], acc[j], 0, 0, 0);
    }
    cur = (cur == 2) ? 0 : cur + 1;
  }
  asm volatile("s_waitcnt vmcnt(0)\n\ts_barrier" ::: "memory");
  __builtin_amdgcn_sched_barrier(0);
#pragma unroll
  for (int ks = 0; ks < 2; ++ks) {
    const int sw = swcol(ks * 32 + quad * 8, l16);
    bf16x8 af = *reinterpret_cast<const bf16x8*>(&As[cur][wm + l16][sw]);
    bf16x8 bfr[4];
#pragma unroll
    for (int j = 0; j < 4; ++j)
      bfr[j] = *reinterpret_cast<const bf16x8*>(&Bs[cur][j * 16 + l16][sw]);
#pragma unroll
    for (int j = 0; j < 4; ++j)
      acc[j] = __builtin_amdgcn_mfma_f32_16x16x32_bf16(af, bfr[j], acc[j], 0, 0, 0);
  }

  // epilogue (flags read only now -> no VMEM during loop besides gl2lds)
  const void* biag = args.bias[z];
  void* Cg         = args.C[z];
  const bool bf32 = args.bIdx[z] >= 0 && args.flags[args.bIdx[z]];
  const bool cf32 = args.cIdx[z] >= 0 && args.flags[args.cIdx[z]];
#pragma unroll
  for (int j = 0; j < 4; ++j) {
    const int col = n0 + j * 16 + l16;
    const float bv = readf(biag, col, bf32);
    const int rowb = m0 + wm + quad * 4;
#pragma unroll
    for (int r = 0; r < 4; ++r) {
      const size_t idx = (size_t)(rowb + r) * N + col;
      const float v = acc[j][r] + bv;
      if (cf32) ((float*)Cg)[idx] = v;
      else      ((bf16_t*)Cg)[idx] = (bf16_t)v;
    }
  }
}

// ---- FUSED K/V/scale/shift projection + modulation: 1024 thr / 16 waves,
// 144 KB 3-slot ring, 4 waves/SIMD, vmcnt(3). Modulation in-register, f32 scale/shift.
struct KsvArgs {
  const bf16_t* A;          // m2b (swizzled)
  const bf16_t* Bt[4];      // wtk, wtv, wts, wtsh (swizzled)
  const void* bias[4]; int bIdx[4];   // bk, bv, bs, bsh
  bf16_t* Kmod;             // [M,512] swcolK (attn kf consumer)
  bf16_t* VtT;              // [B][H][HD][S] swcol
  const int* flags;
};

__global__ __launch_bounds__(1024) void ksv_kernel(KsvArgs args) {
  constexpr int K = 512;
  __shared__ bf16_t As[3][128][64];       // 48 KB
  __shared__ bf16_t Bs[3][4][64][64];     // 96 KB
  const int m0 = blockIdx.x * 128, n0 = blockIdx.y * 64;
  const int t = threadIdx.x, lane = t & 63, wave = t >> 6;   // 0..15
  const int l16 = lane & 15, quad = lane >> 4;
  const int wm = (wave >> 2) * 32;        // 0,32,64,96
  const int wn = (wave & 3) * 16;         // 0,16,32,48
  const int lr = lane >> 3, lc = (lane & 7) * 8;

  auto stage = [&](int slot, int k0) {
    // A: 16 loads, one per wave
    gl2lds(args.A + (size_t)(m0 + wave * 8 + lr) * K + k0 + lc, &As[slot][wave * 8][0]);
    // B: 32 loads, two per wave: mat = wave>>2, rows (wave&3)*16 + {0,8}
    const int mat = wave >> 2;
    const int rb = (wave & 3) * 16;
#pragma unroll
    for (int s = 0; s < 2; ++s) {
      const int r = rb + s * 8;
      gl2lds(args.Bt[mat] + (size_t)(n0 + r + lr) * K + k0 + lc, &Bs[slot][mat][r][0]);
    }
  };

  f32x4 acc[4][2] = {};   // [mat: K,V,S,Sh][mi]

  stage(0, 0);
  stage(1, 64);

  constexpr int NT = K / 64;   // 8
  int cur = 0;
  for (int kt = 0; kt < NT - 1; ++kt) {
    asm volatile("s_waitcnt vmcnt(3)\n\ts_barrier" ::: "memory");
    __builtin_amdgcn_sched_barrier(0);
    if (kt + 2 < NT) {
      const int slot2 = cur == 0 ? 2 : cur - 1;
      stage(slot2, (kt + 2) * 64);
    }
#pragma unroll
    for (int ks = 0; ks < 2; ++ks) {
      const int sw = swcol(ks * 32 + quad * 8, l16);
      bf16x8 af[2], bfr[4];
#pragma unroll
      for (int mi = 0; mi < 2; ++mi)
        af[mi] = *reinterpret_cast<const bf16x8*>(&As[cur][wm + mi * 16 + l16][sw]);
#pragma unroll
      for (int mat = 0; mat < 4; ++mat)
        bfr[mat] = *reinterpret_cast<const bf16x8*>(&Bs[cur][mat][wn + l16][sw]);
#pragma unroll
      for (int mat = 0; mat < 4; ++mat)
#pragma unroll
        for (int mi = 0; mi < 2; ++mi)
          acc[mat][mi] = __builtin_amdgcn_mfma_f32_16x16x32_bf16(af[mi], bfr[mat], acc[mat][mi], 0, 0, 0);
    }
    cur = (cur == 2) ? 0 : cur + 1;
  }
  asm volatile("s_waitcnt vmcnt(0)\n\ts_barrier" ::: "memory");
  __builtin_amdgcn_sched_barrier(0);
#pragma unroll
  for (int ks = 0; ks < 2; ++ks) {
    const int sw = swcol(ks * 32 + quad * 8, l16);
    bf16x8 af[2], bfr[4];
#pragma unroll
    for (int mi = 0; mi < 2; ++mi)
      af[mi] = *reinterpret_cast<const bf16x8*>(&As[cur][wm + mi * 16 + l16][sw]);
#pragma unroll
    for (int mat = 0; mat < 4; ++mat)
      bfr[mat] = *reinterpret_cast<const bf16x8*>(&Bs[cur][mat][wn + l16][sw]);
#pragma unroll
    for (int mat = 0; mat < 4; ++mat)
#pragma unroll
      for (int mi = 0; mi < 2; ++mi)
        acc[mat][mi] = __builtin_amdgcn_mfma_f32_16x16x32_bf16(af[mi], bfr[mat], acc[mat][mi], 0, 0, 0);
  }

  // fused epilogue: s = S+bs, sh = Sh+bsh (f32, unrounded); K' = (K+bk)*s+sh; V' likewise.
  const int col = n0 + wn + l16;
  const float bk  = readf(args.bias[0], col, args.bIdx[0] >= 0 && args.flags[args.bIdx[0]]);
  const float bv  = readf(args.bias[1], col, args.bIdx[1] >= 0 && args.flags[args.bIdx[1]]);
  const float bs  = readf(args.bias[2], col, args.bIdx[2] >= 0 && args.flags[args.bIdx[2]]);
  const float bsh = readf(args.bias[3], col, args.bIdx[3] >= 0 && args.flags[args.bIdx[3]]);
  const int hh = col >> 6, dd = col & 63;
#pragma unroll
  for (int mi = 0; mi < 2; ++mi) {
    const int rowb = m0 + wm + mi * 16 + quad * 4;
    bf16x4 vpack;
#pragma unroll
    for (int r = 0; r < 4; ++r) {
      const int row = rowb + r;
      const float s  = acc[2][mi][r] + bs;
      const float sh = acc[3][mi][r] + bsh;
      const float kk = fmaf(acc[0][mi][r] + bk, s, sh);
      const float vv = fmaf(acc[1][mi][r] + bv, s, sh);
      args.Kmod[(size_t)row * 512 + swcolK(col, row)] = (bf16_t)kk;
      vpack[r] = (bf16_t)vv;
    }
    const int bb = rowb >> 11;      // batch (tile never crosses batch)
    const int ss = rowb & 2047;     // seq (multiple of 4)
    *reinterpret_cast<bf16x4*>(
        args.VtT + (((size_t)(bb * H_ + hh)) * HD_ + dd) * S_ + swcol(ss, dd)) = vpack;
  }
}

// ---- flash attention v15: v14 + CE folded into Q (S arrives pre-scaled; removes
// 16 v_mul per wave-iter from the hot loop). Fused Q-projection prologue as v14.
__global__ __launch_bounds__(512) void attn_kernel(const bf16_t* M1, const bf16_t* Wq,
                                                   const void* bq, const int* flags,
                                                   const bf16_t* Kb, const bf16_t* Vt,
                                                   bf16_t* O) {
  __shared__ bf16_t Ks[3][64][64];    // 24 KB (Q-A rows 0-63 in prologue; K ring in loop)
  __shared__ bf16_t Vs[3][64][64];    // 24 KB (Q-A rows 64-127; V ring)
  __shared__ bf16_t Xs[3][64][64];    // 24 KB (Wq tile in prologue; Qls after)
  const int i = blockIdx.x;
  const int xcd = i & 7, g = i >> 3;     // g in 0..63
  const int slice = xcd * 4 + (g & 3);   // (b,h): 4 slices per XCD
  const int qt = g >> 2;                 // 0..15
  const int b = slice >> 3, h = slice & 7;
  const int t = threadIdx.x, wave = t >> 6, lane = t & 63;   // wave 0..7
  const int l16 = lane & 15, quad = lane >> 4;
  const int q0 = qt * 128 + wave * 16;   // 16 q-rows per wave
  const int lr = lane >> 3, lc = (lane & 7) * 8;

  constexpr float CE = 0.18033688011112042f;  // 0.125 * log2(e), folded into Q

  const size_t q0g = (size_t)b * S_ + qt * 128;   // global base row of this block's Q tile

  // ================= Q-GEMM prologue =================
  auto qstage = [&](int set, int k0) {
#pragma unroll
    for (int s = 0; s < 2; ++s) {
      const int r = wave * 16 + s * 8;   // 0..120
      bf16_t* dst = (wave < 4) ? &Ks[set][r][0] : &Vs[set][r - 64][0];
      gl2lds(M1 + (q0g + r + lr) * D_ + k0 + lc, dst);
    }
    gl2lds(Wq + (size_t)(h * HD_ + wave * 8 + lr) * D_ + k0 + lc, &Xs[set][wave * 8][0]);
  };

  f32x4 qacc[4] = {};
  const bf16_t* brow = (wave < 4) ? &Ks[0][wave * 16][0] : &Vs[0][wave * 16 - 64][0];
  const int setstride = 64 * 64;

  auto qcompute = [&](int set) {
    const bf16_t* bbase = brow + set * setstride;
#pragma unroll
    for (int ks = 0; ks < 2; ++ks) {
      const int sw = swcol(ks * 32 + quad * 8, l16);
      bf16x8 bf = *reinterpret_cast<const bf16x8*>(bbase + l16 * 64 + sw);
      bf16x8 af[4];
#pragma unroll
      for (int j = 0; j < 4; ++j)
        af[j] = *reinterpret_cast<const bf16x8*>(&Xs[set][j * 16 + l16][sw]);
#pragma unroll
      for (int j = 0; j < 4; ++j)
        qacc[j] = __builtin_amdgcn_mfma_f32_16x16x32_bf16(af[j], bf, qacc[j], 0, 0, 0);
    }
  };

  qstage(0, 0);
  qstage(1, 64);
  {
    constexpr int QNT = D_ / 64;   // 8
    int cur = 0;
    for (int kt = 0; kt < QNT - 1; ++kt) {
      asm volatile("s_waitcnt vmcnt(3)\n\ts_barrier" ::: "memory");
      __builtin_amdgcn_sched_barrier(0);
      if (kt + 2 < QNT) {
        const int slot2 = cur == 0 ? 2 : cur - 1;
        qstage(slot2, (kt + 2) * 64);
      }
      qcompute(cur);
      cur = (cur == 2) ? 0 : cur + 1;
    }
    asm volatile("s_waitcnt vmcnt(0)\n\ts_barrier" ::: "memory");
    __builtin_amdgcn_sched_barrier(0);
    qcompute(cur);
  }
  // bias (+bq) in f32, then *CE, one rounding to bf16 (scale folded into Q)
  const bool qbf32 = flags[3] != 0;
  __syncthreads();   // all waves done reading Xs B-frags before Qls overwrite
  bf16_t* qls = &Xs[0][0][0];   // [8 waves][16 q][64 d], spans Xs[0..1]
#pragma unroll
  for (int j = 0; j < 4; ++j) {
    bf16x4 pk;
#pragma unroll
    for (int r = 0; r < 4; ++r) {
      const int d = j * 16 + quad * 4 + r;
      pk[r] = (bf16_t)((qacc[j][r] + readf(bq, h * HD_ + d, qbf32)) * CE);
    }
    *reinterpret_cast<bf16x4*>(&qls[wave * 1024 + l16 * 64 + swcol(j * 16 + quad * 4, l16)]) = pk;
  }
  __syncthreads();
  bf16x8 qf[2];
#pragma unroll
  for (int dc = 0; dc < 2; ++dc)
    qf[dc] = *reinterpret_cast<const bf16x8*>(&qls[wave * 1024 + l16 * 64 + swcol(dc * 32 + quad * 8, l16)]);
  // ================= end prologue =================

  bf16x8 ones;
#pragma unroll
  for (int j = 0; j < 8; ++j) ones[j] = (bf16_t)1.0f;

  f32x4 oacc[4] = {};
  f32x4 lacc = {};

  const size_t kbase = (size_t)b * S_ * D_ + h * HD_;
  const size_t vbase = ((size_t)(b * H_ + h)) * HD_ * S_;

  const int rbase = ((l16 >> 2) << 3) | (l16 & 3);
  int koff[2][4];   // [dc][j]
#pragma unroll
  for (int j = 0; j < 4; ++j) {
    const int rho = rbase + (j >> 1) * 32 + (j & 1) * 4;
#pragma unroll
    for (int dc = 0; dc < 2; ++dc)
      koff[dc][j] = rho * 64 + swcolK(dc * 32 + quad * 8, rho);
  }
  const int voff[2] = { swcol(quad * 8, l16), swcol(32 + quad * 8, l16) };

  auto stage = [&](int slot, int k0) {
    const int r = wave * 8;
    gl2lds(Kb + kbase + (size_t)(k0 + r + lr) * D_ + lc, &Ks[slot][r][0]);
    gl2lds(Vt + vbase + (size_t)(r + lr) * S_ + k0 + lc, &Vs[slot][r][0]);
  };

  auto compute = [&](int cur) {
    f32x4 sacc[4] = {};
    const bf16_t* ksbase = &Ks[cur][0][0];
#pragma unroll
    for (int dc = 0; dc < 2; ++dc) {
      bf16x8 kf[4];
#pragma unroll
      for (int j = 0; j < 4; ++j)
        kf[j] = *reinterpret_cast<const bf16x8*>(ksbase + koff[dc][j]);
#pragma unroll
      for (int j = 0; j < 4; ++j)
        sacc[j] = __builtin_amdgcn_mfma_f32_16x16x32_bf16(kf[j], qf[dc], sacc[j], 0, 0, 0);
    }
#pragma unroll
    for (int kc = 0; kc < 2; ++kc) {
      bf16x8 vf[4];
#pragma unroll
      for (int dj = 0; dj < 4; ++dj)
        vf[dj] = *reinterpret_cast<const bf16x8*>(&Vs[cur][dj * 16 + l16][voff[kc]]);
      bf16x8 bp;
#pragma unroll
      for (int r = 0; r < 4; ++r) {
        bp[r]     = (bf16_t)__builtin_amdgcn_exp2f(fminf(sacc[kc * 2][r],     57.5f));
        bp[4 + r] = (bf16_t)__builtin_amdgcn_exp2f(fminf(sacc[kc * 2 + 1][r], 57.5f));
      }
#pragma unroll
      for (int dj = 0; dj < 4; ++dj)
        oacc[dj] = __builtin_amdgcn_mfma_f32_16x16x32_bf16(vf[dj], bp, oacc[dj], 0, 0, 0);
      lacc = __builtin_amdgcn_mfma_f32_16x16x32_bf16(ones, bp, lacc, 0, 0, 0);
    }
  };

  // drain bias/flag loads so the loop's vmcnt ledger counts only gl2lds ops
  asm volatile("s_waitcnt vmcnt(0)" ::: "memory");
  stage(0, 0);
  stage(1, 64);

  constexpr int NT = S_ / 64;   // 32
  int cur = 0;
  for (int kt = 0; kt < NT - 1; ++kt) {
    asm volatile("s_waitcnt vmcnt(2)\n\ts_barrier" ::: "memory");
    __builtin_amdgcn_sched_barrier(0);
    if (kt + 2 < NT) {
      const int slot2 = cur == 0 ? 2 : cur - 1;   // (kt+2)%3, freed at barrier above
      stage(slot2, (kt + 2) * 64);
    }
    compute(cur);
    cur = (cur == 2) ? 0 : cur + 1;
  }
  asm volatile("s_waitcnt vmcnt(0)\n\ts_barrier" ::: "memory");
  __builtin_amdgcn_sched_barrier(0);
  compute(cur);

  // ---- epilogue: O[q][d] = O^T[d][q] / l[q]; packed 8B stores, SWIZZLED (feeds g2) ----
  {
    const float linv = 1.0f / fmaxf(lacc[0], 1e-30f);
    const int q = q0 + l16;
    const size_t orow = ((size_t)b * S_ + q) * D_ + h * HD_;
#pragma unroll
    for (int dj = 0; dj < 4; ++dj) {
      bf16x4 pack;
#pragma unroll
      for (int r = 0; r < 4; ++r) pack[r] = (bf16_t)(oacc[dj][r] * linv);
      *reinterpret_cast<bf16x4*>(&O[orow + swcol(dj * 16 + quad * 4, q)]) = pack;
    }
  }
}

// ---------------- host launcher ----------------
extern "C" void kernel_launch(void* const* d_in, const int* in_sizes, int n_in,
                              void* d_out, int out_size, void* d_ws, size_t ws_size,
                              hipStream_t stream) {
  (void)n_in; (void)out_size; (void)ws_size;

  char* ws = (char*)d_ws;
  auto alloc = [&](size_t bytes) -> char* {
    char* p = ws; ws += (bytes + 255) & ~(size_t)255; return p;
  };
  int* flags = (int*)alloc(64 * sizeof(int));
  const size_t wbytes = (size_t)512 * 512 * sizeof(bf16_t);
  const size_t fbytes = (size_t)M_ * D_ * sizeof(bf16_t);
  bf16_t* wt    = (bf16_t*)alloc(6 * wbytes);  // 3 MB (swizzled)
  bf16_t* m1b   = (bf16_t*)alloc(fbytes);      // 8 MB mod1 bf16 swizzled (live into attn)
  bf16_t* m2b   = (bf16_t*)alloc(fbytes);      // 8 MB mod2 bf16 swizzled
  bf16_t* vtb   = (bf16_t*)alloc(fbytes);      // 8 MB V^T (swizzled)
  bf16_t* atmp  = (bf16_t*)alloc(fbytes);      // 8 MB attn output (swizzled)
  bf16_t* kmod  = (bf16_t*)alloc(fbytes);      // 8 MB swizzled (swcolK)
  bf16_t* attn_b = atmp;

  bf16_t* wtq  = wt + 0 * 512 * 512;
  bf16_t* wtk  = wt + 1 * 512 * 512;
  bf16_t* wtv  = wt + 2 * 512 * 512;
  bf16_t* wts  = wt + 3 * 512 * 512;
  bf16_t* wtsh = wt + 4 * 512 * 512;
  bf16_t* wto  = wt + 5 * 512 * 512;

  // prep: cvt (2048) + weight transpose (384, self-detect) + flags (14) — one dispatch
  PrepArgs pa;
  pa.csrc[0] = d_in[0]; pa.cdst[0] = m1b;
  pa.csrc[1] = d_in[1]; pa.cdst[1] = m2b;
  const int widx[6] = {2, 4, 6, 10, 12, 8};
  bf16_t* wdst[6] = {wtq, wtk, wtv, wts, wtsh, wto};
  for (int i = 0; i < 6; ++i) { pa.wsrc[i] = d_in[widx[i]]; pa.wdst[i] = wdst[i]; }
  for (int i = 0; i < NIN; ++i) {
    pa.dp[i] = (const uint16_t*)d_in[i];
    pa.dn[i] = in_sizes[i] < 2048 ? in_sizes[i] : 2048;
  }
  pa.flags = flags;
  hipLaunchKernelGGL(prep_kernel, dim3(2048 + 384 + 14), dim3(256), 0, stream, pa);

  // ksv: fused K/V/scale/shift + modulation — 512 blocks x 1024 thr (4 waves/SIMD)
  KsvArgs kv;
  kv.A = m2b;
  kv.Bt[0] = wtk; kv.Bt[1] = wtv; kv.Bt[2] = wts; kv.Bt[3] = wtsh;
  kv.bias[0] = d_in[5];  kv.bIdx[0] = 5;
  kv.bias[1] = d_in[7];  kv.bIdx[1] = 7;
  kv.bias[2] = d_in[11]; kv.bIdx[2] = 11;
  kv.bias[3] = d_in[13]; kv.bIdx[3] = 13;
  kv.Kmod = kmod; kv.VtT = vtb;
  kv.flags = flags;
  hipLaunchKernelGGL(ksv_kernel, dim3(M_ / 128, 8), dim3(1024), 0, stream, kv);

  // attn (+ fused Q projection, CE folded into Q): 512 blocks x 512 threads
  hipLaunchKernelGGL(attn_kernel, dim3(512), dim3(512), 0, stream,
                     m1b, wtq, d_in[3], flags, kmod, vtb, attn_b);

  // g2: out = attn @ Wo^T + bo — 512 blocks x 512 thr
  GemmBatch g2;
  for (int i = 0; i < 3; ++i) {
    g2.A[i] = attn_b;
    g2.Bt[i] = wto;
    g2.bias[i] = d_in[9]; g2.bIdx[i] = 9;
    g2.C[i] = d_out; g2.cIdx[i] = 0;
  }
  g2.flags = flags;
  hipLaunchKernelGGL(gemm_bt_kernel, dim3(M_ / 128, 8, 1), dim3(512), 0, stream, g2);
}